// Round 15
// baseline (59.789 us; speedup 1.0000x reference)
//
#include <hip/hip_runtime.h>

// MyConvT: masked ConvTranspose2d, B=8, Cin=192, Cout=128, 64x64 -> 128x128,
// K=5, S=2, P=2, OP=1.  out = pooled_mask ? (convT(x,w) + bias) : 0
// Round 14 = r13 + seam dissolution: the two round-boundary full drains
// (barrier/stage_x/vmcnt(0)/barrier) are folded into the counted ledger.
// Plane liveness: p3 last read t8, p2 t18, p0/p1 t24 => planes 2,3 of round
// c3+1 restage inside t22's bundle (all waves past t20's barrier => t18
// reads consumed); planes 0,1 restage at the boundary with NO drain and ONE
// barrier. Gates (per-wave min-count ledger, a=b=4): t22/t24 vmcnt(10) for
// c3<2; t0 vmcnt(10) for c3>0 (6 for c3=0); steady vmcnt(6); c3=2 tail 2/0.
// In-order vmcnt retirement => boundary-x landed by its first reader's gate.

#define NB   8
#define CIN  192
#define COUT 128
#define HH   64
#define OHH  128
#define OWW  128
#define MH   132
#define MW   132

#define X4_IYH_B 27648               // bytes per (b,iyH): 3 c3 x 72 rows x 128B
#define PLANE_B  9216                // one c3 plane slice: 72 rows x 128B
#define XBUF_B   36864               // 4 planes
#define WOFF     36864
#define NSLOT    5
#define LDS_B    (XBUF_B + NSLOT * 8192)   // 77,824 <= 81,920 (2 blocks/CU)

typedef short bf16x8 __attribute__((ext_vector_type(8)));
typedef float f32x4  __attribute__((ext_vector_type(4)));
typedef float f32x2  __attribute__((ext_vector_type(2)));

static __device__ __forceinline__ unsigned short f2bf(float f) {
  union { float f; unsigned int u; } a; a.f = f;
  return (unsigned short)((a.u + 0x7fffu + ((a.u >> 16) & 1u)) >> 16);   // RNE
}

#define GLOAD_LDS16(gp, lp) __builtin_amdgcn_global_load_lds(                      \
    (const __attribute__((address_space(1))) void*)(gp),                           \
    (__attribute__((address_space(3))) void*)(lp), 16, 0, 0)

// ---------------- fused prep: xpose (528) | wpack (96) | pool (128) --------
__global__ __launch_bounds__(256) void prep_k(
    const float* __restrict__ x, const int* __restrict__ mask,
    const float* __restrict__ w, unsigned short* __restrict__ x4,
    unsigned short* __restrict__ w4, unsigned char* __restrict__ many) {
  const int bid = blockIdx.x, tid = threadIdx.x;

  if (bid < 528) {                                   // ---- xpose ----
    const int b = bid / 66, iyH = bid % 66;
    const int lane = tid & 63, wv = tid >> 6;
    unsigned short* pl = x4 + (size_t)(b * 66 + iyH) * (X4_IYH_B / 2);

    if (iyH == 0 || iyH == 65) {                     // zero halo plane
      for (int i = tid; i < X4_IYH_B / 16; i += 256)
        *(uint4*)(pl + i * 8) = make_uint4(0, 0, 0, 0);
      return;
    }
    const int iy = iyH - 1;
    if (tid < 48) {                                  // halo rows 0,65 per c3
      int c3 = tid >> 4, rr = (tid >> 3) & 1, ch = tid & 7;
      *(uint4*)(pl + (c3 * 72 + rr * 65) * 64 + ch * 8) = make_uint4(0, 0, 0, 0);
    }
    #pragma unroll
    for (int k = 0; k < 6; ++k) {
      int ci0 = wv * 48 + k * 8;
      int c3 = ci0 >> 6, cr = ci0 & 63;
      unsigned short p[8];
      #pragma unroll
      for (int e = 0; e < 8; ++e)
        p[e] = f2bf(x[(((size_t)b * CIN + ci0 + e) * HH + iy) * HH + lane]);
      uint4 v;
      v.x = (unsigned)p[0] | ((unsigned)p[1] << 16);
      v.y = (unsigned)p[2] | ((unsigned)p[3] << 16);
      v.z = (unsigned)p[4] | ((unsigned)p[5] << 16);
      v.w = (unsigned)p[6] | ((unsigned)p[7] << 16);
      *(uint4*)(pl + ((size_t)c3 * 72 + 1 + lane) * 64 + cr) = v;
    }
  } else if (bid < 624) {                            // ---- wpack ----
    int idx = (bid - 528) * 256 + tid;               // 0..24575
    int ci = idx % CIN, co = idx / CIN;
    int cob = co >> 6, c = co & 63, c3 = ci >> 6, cir = ci & 63;
    const float* src = w + (size_t)(ci * COUT + co) * 25;
    #pragma unroll
    for (int tap = 0; tap < 25; ++tap)
      w4[(size_t)((tap * 2 + cob) * 3 + c3) * 4096 + c * 64 + cir] = f2bf(src[tap]);
  } else {                                           // ---- pool (4 ow/thr) ----
    int g = (bid - 624) * 256 + tid;                 // 0..32767
    int owq = g & 31, oh = (g >> 5) & 127, b = g >> 12;
    const int* mp = mask + (b * MH + oh) * MW + owq * 4;
    int a0 = 0, a1 = 0, a2 = 0, a3 = 0;
    #pragma unroll
    for (int i = 0; i < 5; ++i) {
      int4 u = *(const int4*)(mp + i * MW);
      int4 v = *(const int4*)(mp + i * MW + 4);
      int c = u.z | u.w | v.x;                       // cols +2,+3,+4
      a0 |= u.x | u.y | c;
      a1 |= u.y | c | v.y;
      a2 |= c | v.y | v.z;
      a3 |= u.w | v.x | v.y | v.z | v.w;
    }
    *(uchar4*)(many + ((size_t)b * OHH + oh) * OWW + owq * 4) =
        make_uchar4(a0 ? 1 : 0, a1 ? 1 : 0, a2 ? 1 : 0, a3 ? 1 : 0);
  }
}

// ------------------------------ main kernel --------------------------------
// flat tap order (pairs aligned to group starts):
// t:      0  1  2  3  4  5  6  7  8  9 10 11 12 13 14 15 16 17 18 19 20 21 22 23 24
// (kh,kw) 00 01 10 11 02 03 12 13 04 14 20 21 30 31 22 23 32 33 24 34 40 41 42 43 44

#define VMC(N) asm volatile("s_waitcnt vmcnt(" #N ")" ::: "memory")

#define BF_LOAD(KK, KJ)                                                        \
  { const int p_ = oyr + 2 - (KK);                                             \
    _Pragma("unroll") for (int k2 = 0; k2 < 2; ++k2)                           \
      _Pragma("unroll") for (int ti = 0; ti < 4; ++ti) {                       \
        const int row_ = ti * 16 + l15 + 2 - (KJ);                             \
        bfr[k2][ti] = *(const bf16x8*)(lds + p_ * PLANE_B + row_ * 128 +       \
                                       (((k2 * 4 + kc) ^ (row_ & 7)) << 4)); } }

#define AF_LOADJ(J, T)                                                         \
  { const char* ws_ = lds + WOFF + ((T) % 5) * 8192;                           \
    _Pragma("unroll") for (int k2 = 0; k2 < 2; ++k2)                           \
      _Pragma("unroll") for (int mi = 0; mi < 2; ++mi) {                       \
        const int row_ = cos * 32 + mi * 16 + l15;                             \
        afr[J][k2][mi] = *(const bf16x8*)(ws_ + row_ * 128 +                   \
                                          (((k2 * 4 + kc) ^ (l15 & 7)) << 4)); } }

#define MMJ(J, PH_, PW_)                                                       \
  { __builtin_amdgcn_s_setprio(1);                                             \
    _Pragma("unroll") for (int k2 = 0; k2 < 2; ++k2)                           \
      _Pragma("unroll") for (int mi = 0; mi < 2; ++mi)                         \
        _Pragma("unroll") for (int ti = 0; ti < 4; ++ti)                       \
          acc[PH_][PW_][mi][ti] = __builtin_amdgcn_mfma_f32_16x16x32_bf16(     \
              afr[J][k2][mi], bfr[k2][ti], acc[PH_][PW_][mi][ti], 0, 0, 0);    \
    __builtin_amdgcn_s_setprio(0); }

// standard pair-phase: stage T+3,T+4 | vmcnt(6)+barrier | (bf) | af x2 | MFMA
#define PAIRB(T, KK, KJ, PH0, PW0, PH1, PW1)                                   \
  { stage_u((T) + 3); stage_u((T) + 4); VMC(6);                                \
    __builtin_amdgcn_s_barrier();                                              \
    BF_LOAD(KK, KJ) AF_LOADJ(0, T) AF_LOADJ(1, (T) + 1)                        \
    MMJ(0, PH0, PW0) MMJ(1, PH1, PW1) }
#define PAIRN(T, PH0, PW0, PH1, PW1)                                           \
  { stage_u((T) + 3); stage_u((T) + 4); VMC(6);                                \
    __builtin_amdgcn_s_barrier();                                              \
    AF_LOADJ(0, T) AF_LOADJ(1, (T) + 1)                                        \
    MMJ(0, PH0, PW0) MMJ(1, PH1, PW1) }
// t0: gate 6 (round 0: prologue ledger) / 10 (rounds 1,2: seam ledger)
#define PAIR0(T, KK, KJ, PH0, PW0, PH1, PW1)                                   \
  { stage_u((T) + 3); stage_u((T) + 4);                                        \
    if (c3 == 0) { VMC(6); } else { VMC(10); }                                 \
    __builtin_amdgcn_s_barrier();                                              \
    BF_LOAD(KK, KJ) AF_LOADJ(0, T) AF_LOADJ(1, (T) + 1)                        \
    MMJ(0, PH0, PW0) MMJ(1, PH1, PW1) }
// t22: + early restage of next round's planes 2,3 (free since t18+2 phases)
#define PAIRX(T, KK, KJ, PH0, PW0, PH1, PW1)                                   \
  { stage_u((T) + 3); stage_u((T) + 4);                                        \
    if (c3 < 2) { stage_xr(c3 + 1, 18, 36); VMC(10); } else { VMC(2); }        \
    __builtin_amdgcn_s_barrier();                                              \
    BF_LOAD(KK, KJ) AF_LOADJ(0, T) AF_LOADJ(1, (T) + 1)                        \
    MMJ(0, PH0, PW0) MMJ(1, PH1, PW1) }
// t24 single-tap: gate 10 (c3<2) / 0 (final drain)
#define PH1BX(T, KK, KJ, PH0, PW0)                                             \
  { stage_u((T) + 3);                                                          \
    if (c3 < 2) { VMC(10); } else { VMC(0); }                                  \
    __builtin_amdgcn_s_barrier();                                              \
    BF_LOAD(KK, KJ) AF_LOADJ(0, T) MMJ(0, PH0, PW0) }

// grid 512: bid&7 = b (== XCD); qq = bid>>3: cob = qq&1, oyq = qq>>1 (0..31).
// 256 thr = 4 waves: cos = wv&1 (co 32-half), oyr = wv>>1 (oy row of pair).
__global__ __launch_bounds__(256, 2) void convt_mfma(
    const unsigned short* __restrict__ x4, const unsigned short* __restrict__ w4,
    const float* __restrict__ bias, const unsigned char* __restrict__ many,
    float* __restrict__ out) {
  __shared__ __align__(16) char lds[LDS_B];
  // tapid (kh*5+kw) by flat tap index
  constexpr int TID[25] = {0,1,5,6, 2,3,7,8, 4,9, 10,11,15,16, 12,13,17,18,
                           14,19, 20,21, 22,23, 24};

  const int tid = threadIdx.x, lane = tid & 63, wv = tid >> 6;
  const int l15 = lane & 15, kc = lane >> 4;
  const int cos = wv & 1, oyr = wv >> 1;
  const int b = blockIdx.x & 7, qq = blockIdx.x >> 3;
  const int cob = qq & 1, oyq = qq >> 1;
  const int oy0 = oyq * 2, oy = oy0 + oyr;
  // inverse-permuted source lane offset (matches read-side XOR swizzle)
  const int sswz = (lane >> 3) * 128 + (((lane & 7) ^ (lane >> 3)) << 4);

  const char* x4b = (const char*)x4 + (size_t)(b * 66 + oy0) * X4_IYH_B;
  const char* w4b = (const char*)w4 + cob * 24576;

  f32x4 acc[2][2][2][4];                 // [ph][pw][mi][ti]
  #pragma unroll
  for (int p = 0; p < 2; ++p)
    #pragma unroll
    for (int q2 = 0; q2 < 2; ++q2)
      #pragma unroll
      for (int i = 0; i < 2; ++i)
        #pragma unroll
        for (int j = 0; j < 4; ++j)
          acc[p][q2][i][j] = (f32x4){0.f, 0.f, 0.f, 0.f};

  // stage x chunks [qlo,qhi) of round c3n: chunk qc -> plane qc/9, 1KB ch qc%9
  auto stage_xr = [&](int c3n, int qlo, int qhi) {
    for (int qc = qlo + wv; qc < qhi; qc += 4) {
      int p = qc / 9, ch = qc % 9;
      GLOAD_LDS16(x4b + (size_t)p * X4_IYH_B + c3n * PLANE_B + ch * 1024 + sswz,
                  lds + p * PLANE_B + ch * 1024 + lane * 16);
    }
  };
  auto stage_w = [&](int tapid, int c3n, int slot) { // 2 x 1KB per wave
    const char* s = w4b + (size_t)tapid * 49152 + c3n * 8192 + wv * 2048 + sswz;
    char* d = lds + WOFF + slot * 8192 + wv * 2048 + lane * 16;
    GLOAD_LDS16(s, d);
    GLOAD_LDS16(s + 1024, d + 1024);
  };
  int c3 = 0;                                        // current ci64 round
  auto stage_u = [&](int u) {                        // stage local-or-next tap u
    if (u <= 24) stage_w(TID[u], c3, u % 5);
    else if (c3 < 2) stage_w(TID[u - 25], c3 + 1, (u - 25) % 5);
  };

  // ---- prologue: x round 0 (all 4 planes) + flat taps 0,1,2 (slots 0,1,2) ----
  stage_xr(0, 0, 36);
  stage_w(TID[0], 0, 0);
  stage_w(TID[1], 0, 1);
  stage_w(TID[2], 0, 2);
  // no wait here: PAIR0(0)'s gate (vmcnt 6) admits taps 2..4 in flight.

  bf16x8 bfr[2][4], afr[2][2][2];
  #pragma unroll 1
  for (c3 = 0; c3 < 3; ++c3) {
    PAIR0(0,  0, 0,  0, 0,  0, 1)       // t0 (0,0), t1 (0,1) | bf g(kk0,kj0)
    PAIRN(2,         1, 0,  1, 1)       // t2 (1,0), t3 (1,1)
    PAIRB(4,  0, 1,  0, 0,  0, 1)       // t4 (0,2), t5 (0,3) | bf g(kk0,kj1)
    PAIRN(6,         1, 0,  1, 1)       // t6 (1,2), t7 (1,3)
    PAIRB(8,  0, 2,  0, 0,  1, 0)       // t8 (0,4), t9 (1,4) | bf g(kk0,kj2)
    PAIRB(10, 1, 0,  0, 0,  0, 1)       // t10 (2,0), t11 (2,1) | bf g(kk1,kj0)
    PAIRN(12,        1, 0,  1, 1)       // t12 (3,0), t13 (3,1)
    PAIRB(14, 1, 1,  0, 0,  0, 1)       // t14 (2,2), t15 (2,3) | bf g(kk1,kj1)
    PAIRN(16,        1, 0,  1, 1)       // t16 (3,2), t17 (3,3)
    PAIRB(18, 1, 2,  0, 0,  1, 0)       // t18 (2,4), t19 (3,4) | bf g(kk1,kj2)
    PAIRB(20, 2, 0,  0, 0,  0, 1)       // t20 (4,0), t21 (4,1) | bf g(kk2,kj0)
    PAIRX(22, 2, 1,  0, 0,  0, 1)       // t22 (4,2), t23 (4,3) | bf g(kk2,kj1)
                                        //   + stage planes 2,3 of round c3+1
    PH1BX(24, 2, 2,  0, 0)              // t24 (4,4)           | bf g(kk2,kj2)
    if (c3 < 2) {                       // seam: planes 0,1 only, no drain
      __builtin_amdgcn_s_barrier();     // all waves' t24 reads consumed
      stage_xr(c3 + 1, 0, 18);
    }
  }

  // ---- epilogue: bias + mask fused, fully-coalesced f32x2 stores ----
  const int cobase = cob * 64 + cos * 32;
  #pragma unroll
  for (int mi = 0; mi < 2; ++mi) {
    const f32x4 bv = *(const f32x4*)(bias + cobase + mi * 16 + kc * 4);
    #pragma unroll
    for (int ph = 0; ph < 2; ++ph) {
      const int oh = 2 * oy + ph;
      const unsigned char* mrow = many + ((size_t)b * OHH + oh) * OWW;
      #pragma unroll
      for (int ti = 0; ti < 4; ++ti) {
        const int ow0 = 2 * (ti * 16 + l15);
        const unsigned short m2 = *(const unsigned short*)(mrow + ow0);
        #pragma unroll
        for (int r = 0; r < 4; ++r) {
          const int co = cobase + mi * 16 + kc * 4 + r;
          f32x2 v;
          v.x = (m2 & 0x00FFu) ? acc[ph][0][mi][ti][r] + bv[r] : 0.f;
          v.y = (m2 & 0xFF00u) ? acc[ph][1][mi][ti][r] + bv[r] : 0.f;
          *(f32x2*)(out + (((size_t)(b * COUT + co)) * OHH + oh) * OWW + ow0) = v;
        }
      }
    }
  }
}

extern "C" void kernel_launch(void* const* d_in, const int* in_sizes, int n_in,
                              void* d_out, int out_size, void* d_ws, size_t ws_size,
                              hipStream_t stream) {
  const float* x    = (const float*)d_in[0];
  const int*   mask = (const int*)d_in[1];
  const float* w    = (const float*)d_in[2];
  const float* bias = (const float*)d_in[3];
  float* out = (float*)d_out;

  // ws: many 128KB | x4 14.6MB | w4 1.23MB  (~16MB)
  unsigned char*  many = (unsigned char*)d_ws;
  unsigned short* x4   = (unsigned short*)((char*)d_ws + 131072);
  unsigned short* w4   = (unsigned short*)((char*)d_ws + 131072 +
                                           (size_t)NB * 66 * X4_IYH_B);

  prep_k<<<752, 256, 0, stream>>>(x, mask, w, x4, w4, many);
  convt_mfma<<<512, 256, 0, stream>>>(x4, w4, bias, many, out);
}

// Round 16
// 55.119 us; speedup vs baseline: 1.0847x; 1.0847x over previous
//
#include <hip/hip_runtime.h>

// MyConvT: masked ConvTranspose2d, B=8, Cin=192, Cout=128, 64x64 -> 128x128,
// K=5, S=2, P=2, OP=1.  out = pooled_mask ? (convT(x,w) + bias) : 0
// Round 15 = exact revert to r13 (best measured: convt 44.4us, total 55.1us).
// r12's bf double-buffer and r14's seam-fold both regressed via register
// spills (FETCH/WRITE inflation at constant VGPR_Count); r14's seam premise
// was also wrong (seam drains ~= L2 latency x2 ~= <1% of kernel).
// Structure: fused prep (1 kernel) + convt at 2 blocks/CU, PAIR-PHASES
// (one vmcnt gate + one barrier per 2 taps), 5-slot w-ring staged 3 ahead
// with counted vmcnt(6) (tail 2/0), x 4-plane buffer restaged per ci64 round.

#define NB   8
#define CIN  192
#define COUT 128
#define HH   64
#define OHH  128
#define OWW  128
#define MH   132
#define MW   132

#define X4_IYH_B 27648               // bytes per (b,iyH): 3 c3 x 72 rows x 128B
#define PLANE_B  9216                // one c3 plane slice: 72 rows x 128B
#define XBUF_B   36864               // 4 planes
#define WOFF     36864
#define NSLOT    5
#define LDS_B    (XBUF_B + NSLOT * 8192)   // 77,824 <= 81,920 (2 blocks/CU)

typedef short bf16x8 __attribute__((ext_vector_type(8)));
typedef float f32x4  __attribute__((ext_vector_type(4)));
typedef float f32x2  __attribute__((ext_vector_type(2)));

static __device__ __forceinline__ unsigned short f2bf(float f) {
  union { float f; unsigned int u; } a; a.f = f;
  return (unsigned short)((a.u + 0x7fffu + ((a.u >> 16) & 1u)) >> 16);   // RNE
}

#define GLOAD_LDS16(gp, lp) __builtin_amdgcn_global_load_lds(                      \
    (const __attribute__((address_space(1))) void*)(gp),                           \
    (__attribute__((address_space(3))) void*)(lp), 16, 0, 0)

// ---------------- fused prep: xpose (528) | wpack (96) | pool (128) --------
__global__ __launch_bounds__(256) void prep_k(
    const float* __restrict__ x, const int* __restrict__ mask,
    const float* __restrict__ w, unsigned short* __restrict__ x4,
    unsigned short* __restrict__ w4, unsigned char* __restrict__ many) {
  const int bid = blockIdx.x, tid = threadIdx.x;

  if (bid < 528) {                                   // ---- xpose ----
    const int b = bid / 66, iyH = bid % 66;
    const int lane = tid & 63, wv = tid >> 6;
    unsigned short* pl = x4 + (size_t)(b * 66 + iyH) * (X4_IYH_B / 2);

    if (iyH == 0 || iyH == 65) {                     // zero halo plane
      for (int i = tid; i < X4_IYH_B / 16; i += 256)
        *(uint4*)(pl + i * 8) = make_uint4(0, 0, 0, 0);
      return;
    }
    const int iy = iyH - 1;
    if (tid < 48) {                                  // halo rows 0,65 per c3
      int c3 = tid >> 4, rr = (tid >> 3) & 1, ch = tid & 7;
      *(uint4*)(pl + (c3 * 72 + rr * 65) * 64 + ch * 8) = make_uint4(0, 0, 0, 0);
    }
    #pragma unroll
    for (int k = 0; k < 6; ++k) {
      int ci0 = wv * 48 + k * 8;
      int c3 = ci0 >> 6, cr = ci0 & 63;
      unsigned short p[8];
      #pragma unroll
      for (int e = 0; e < 8; ++e)
        p[e] = f2bf(x[(((size_t)b * CIN + ci0 + e) * HH + iy) * HH + lane]);
      uint4 v;
      v.x = (unsigned)p[0] | ((unsigned)p[1] << 16);
      v.y = (unsigned)p[2] | ((unsigned)p[3] << 16);
      v.z = (unsigned)p[4] | ((unsigned)p[5] << 16);
      v.w = (unsigned)p[6] | ((unsigned)p[7] << 16);
      *(uint4*)(pl + ((size_t)c3 * 72 + 1 + lane) * 64 + cr) = v;
    }
  } else if (bid < 624) {                            // ---- wpack ----
    int idx = (bid - 528) * 256 + tid;               // 0..24575
    int ci = idx % CIN, co = idx / CIN;
    int cob = co >> 6, c = co & 63, c3 = ci >> 6, cir = ci & 63;
    const float* src = w + (size_t)(ci * COUT + co) * 25;
    #pragma unroll
    for (int tap = 0; tap < 25; ++tap)
      w4[(size_t)((tap * 2 + cob) * 3 + c3) * 4096 + c * 64 + cir] = f2bf(src[tap]);
  } else {                                           // ---- pool (4 ow/thr) ----
    int g = (bid - 624) * 256 + tid;                 // 0..32767
    int owq = g & 31, oh = (g >> 5) & 127, b = g >> 12;
    const int* mp = mask + (b * MH + oh) * MW + owq * 4;
    int a0 = 0, a1 = 0, a2 = 0, a3 = 0;
    #pragma unroll
    for (int i = 0; i < 5; ++i) {
      int4 u = *(const int4*)(mp + i * MW);
      int4 v = *(const int4*)(mp + i * MW + 4);
      int c = u.z | u.w | v.x;                       // cols +2,+3,+4
      a0 |= u.x | u.y | c;
      a1 |= u.y | c | v.y;
      a2 |= c | v.y | v.z;
      a3 |= u.w | v.x | v.y | v.z | v.w;
    }
    *(uchar4*)(many + ((size_t)b * OHH + oh) * OWW + owq * 4) =
        make_uchar4(a0 ? 1 : 0, a1 ? 1 : 0, a2 ? 1 : 0, a3 ? 1 : 0);
  }
}

// ------------------------------ main kernel --------------------------------
// flat tap order (pairs aligned to group starts):
// t:      0  1  2  3  4  5  6  7  8  9 10 11 12 13 14 15 16 17 18 19 20 21 22 23 24
// (kh,kw) 00 01 10 11 02 03 12 13 04 14 20 21 30 31 22 23 32 33 24 34 40 41 42 43 44

#define VMC(N) asm volatile("s_waitcnt vmcnt(" #N ")" ::: "memory")

#define GATE(T)                                                                \
  { if ((T) == 24 && c3 == 2)      VMC(0);                                     \
    else if ((T) == 22 && c3 == 2) VMC(2);                                     \
    else                           VMC(6);                                     \
    __builtin_amdgcn_s_barrier(); }

#define BF_LOAD(KK, KJ)                                                        \
  { const int p_ = oyr + 2 - (KK);                                             \
    _Pragma("unroll") for (int k2 = 0; k2 < 2; ++k2)                           \
      _Pragma("unroll") for (int ti = 0; ti < 4; ++ti) {                       \
        const int row_ = ti * 16 + l15 + 2 - (KJ);                             \
        bfr[k2][ti] = *(const bf16x8*)(lds + p_ * PLANE_B + row_ * 128 +       \
                                       (((k2 * 4 + kc) ^ (row_ & 7)) << 4)); } }

#define AF_LOADJ(J, T)                                                         \
  { const char* ws_ = lds + WOFF + ((T) % 5) * 8192;                           \
    _Pragma("unroll") for (int k2 = 0; k2 < 2; ++k2)                           \
      _Pragma("unroll") for (int mi = 0; mi < 2; ++mi) {                       \
        const int row_ = cos * 32 + mi * 16 + l15;                             \
        afr[J][k2][mi] = *(const bf16x8*)(ws_ + row_ * 128 +                   \
                                          (((k2 * 4 + kc) ^ (l15 & 7)) << 4)); } }

#define MMJ(J, PH_, PW_)                                                       \
  { __builtin_amdgcn_s_setprio(1);                                             \
    _Pragma("unroll") for (int k2 = 0; k2 < 2; ++k2)                           \
      _Pragma("unroll") for (int mi = 0; mi < 2; ++mi)                         \
        _Pragma("unroll") for (int ti = 0; ti < 4; ++ti)                       \
          acc[PH_][PW_][mi][ti] = __builtin_amdgcn_mfma_f32_16x16x32_bf16(     \
              afr[J][k2][mi], bfr[k2][ti], acc[PH_][PW_][mi][ti], 0, 0, 0);    \
    __builtin_amdgcn_s_setprio(0); }

// pair-phase: stage taps T+3,T+4 | gate+barrier | (bf reload) | af x2 | MFMA x32
#define PAIRB(T, KK, KJ, PH0, PW0, PH1, PW1)                                   \
  { stage_u((T) + 3); stage_u((T) + 4); GATE(T)                                \
    BF_LOAD(KK, KJ) AF_LOADJ(0, T) AF_LOADJ(1, (T) + 1)                        \
    MMJ(0, PH0, PW0) MMJ(1, PH1, PW1) }
#define PAIRN(T, PH0, PW0, PH1, PW1)                                           \
  { stage_u((T) + 3); stage_u((T) + 4); GATE(T)                                \
    AF_LOADJ(0, T) AF_LOADJ(1, (T) + 1)                                        \
    MMJ(0, PH0, PW0) MMJ(1, PH1, PW1) }
// single-tap phase (t=24): stages only T+3 (keeps cross-round ledger uniform)
#define PH1B(T, KK, KJ, PH0, PW0)                                              \
  { stage_u((T) + 3); GATE(T)                                                  \
    BF_LOAD(KK, KJ) AF_LOADJ(0, T) MMJ(0, PH0, PW0) }

// grid 512: bid&7 = b (== XCD); qq = bid>>3: cob = qq&1, oyq = qq>>1 (0..31).
// 256 thr = 4 waves: cos = wv&1 (co 32-half), oyr = wv>>1 (oy row of pair).
__global__ __launch_bounds__(256, 2) void convt_mfma(
    const unsigned short* __restrict__ x4, const unsigned short* __restrict__ w4,
    const float* __restrict__ bias, const unsigned char* __restrict__ many,
    float* __restrict__ out) {
  __shared__ __align__(16) char lds[LDS_B];
  // tapid (kh*5+kw) by flat tap index
  constexpr int TID[25] = {0,1,5,6, 2,3,7,8, 4,9, 10,11,15,16, 12,13,17,18,
                           14,19, 20,21, 22,23, 24};

  const int tid = threadIdx.x, lane = tid & 63, wv = tid >> 6;
  const int l15 = lane & 15, kc = lane >> 4;
  const int cos = wv & 1, oyr = wv >> 1;
  const int b = blockIdx.x & 7, qq = blockIdx.x >> 3;
  const int cob = qq & 1, oyq = qq >> 1;
  const int oy0 = oyq * 2, oy = oy0 + oyr;
  // inverse-permuted source lane offset (matches read-side XOR swizzle)
  const int sswz = (lane >> 3) * 128 + (((lane & 7) ^ (lane >> 3)) << 4);

  const char* x4b = (const char*)x4 + (size_t)(b * 66 + oy0) * X4_IYH_B;
  const char* w4b = (const char*)w4 + cob * 24576;

  f32x4 acc[2][2][2][4];                 // [ph][pw][mi][ti]
  #pragma unroll
  for (int p = 0; p < 2; ++p)
    #pragma unroll
    for (int q2 = 0; q2 < 2; ++q2)
      #pragma unroll
      for (int i = 0; i < 2; ++i)
        #pragma unroll
        for (int j = 0; j < 4; ++j)
          acc[p][q2][i][j] = (f32x4){0.f, 0.f, 0.f, 0.f};

  auto stage_x = [&](int c3n) {
    #pragma unroll
    for (int j = 0; j < 9; ++j) {
      int qc = wv + 4 * j;                           // 36 chunks of 1KB
      int p = qc / 9, ch = qc % 9;
      GLOAD_LDS16(x4b + (size_t)p * X4_IYH_B + c3n * PLANE_B + ch * 1024 + sswz,
                  lds + p * PLANE_B + ch * 1024 + lane * 16);
    }
  };
  auto stage_w = [&](int tapid, int c3n, int slot) { // 2 x 1KB per wave
    const char* s = w4b + (size_t)tapid * 49152 + c3n * 8192 + wv * 2048 + sswz;
    char* d = lds + WOFF + slot * 8192 + wv * 2048 + lane * 16;
    GLOAD_LDS16(s, d);
    GLOAD_LDS16(s + 1024, d + 1024);
  };
  int c3 = 0;                                        // current ci64 round
  auto stage_u = [&](int u) {                        // stage local-or-next tap u
    if (u <= 24) stage_w(TID[u], c3, u % 5);
    else if (c3 < 2) stage_w(TID[u - 25], c3 + 1, (u - 25) % 5);
  };

  // ---- prologue: x round 0 + flat taps 0,1,2 (slots 0,1,2) ----
  stage_x(0);
  stage_w(TID[0], 0, 0);
  stage_w(TID[1], 0, 1);
  stage_w(TID[2], 0, 2);
  // no wait here: PAIRB(0)'s gate (vmcnt 6) admits taps 2..4 in flight.

  bf16x8 bfr[2][4], afr[2][2][2];
  #pragma unroll 1
  for (c3 = 0; c3 < 3; ++c3) {
    PAIRB(0,  0, 0,  0, 0,  0, 1)       // t0 (0,0), t1 (0,1) | bf g(kk0,kj0)
    PAIRN(2,         1, 0,  1, 1)       // t2 (1,0), t3 (1,1)
    PAIRB(4,  0, 1,  0, 0,  0, 1)       // t4 (0,2), t5 (0,3) | bf g(kk0,kj1)
    PAIRN(6,         1, 0,  1, 1)       // t6 (1,2), t7 (1,3)
    PAIRB(8,  0, 2,  0, 0,  1, 0)       // t8 (0,4), t9 (1,4) | bf g(kk0,kj2)
    PAIRB(10, 1, 0,  0, 0,  0, 1)       // t10 (2,0), t11 (2,1) | bf g(kk1,kj0)
    PAIRN(12,        1, 0,  1, 1)       // t12 (3,0), t13 (3,1)
    PAIRB(14, 1, 1,  0, 0,  0, 1)       // t14 (2,2), t15 (2,3) | bf g(kk1,kj1)
    PAIRN(16,        1, 0,  1, 1)       // t16 (3,2), t17 (3,3)
    PAIRB(18, 1, 2,  0, 0,  1, 0)       // t18 (2,4), t19 (3,4) | bf g(kk1,kj2)
    PAIRB(20, 2, 0,  0, 0,  0, 1)       // t20 (4,0), t21 (4,1) | bf g(kk2,kj0)
    PAIRB(22, 2, 1,  0, 0,  0, 1)       // t22 (4,2), t23 (4,3) | bf g(kk2,kj1)
    PH1B (24, 2, 2,  0, 0)              // t24 (4,4)           | bf g(kk2,kj2)
    if (c3 < 2) {                       // round boundary: restage x planes
      __builtin_amdgcn_s_barrier();     // all waves done reading xbuf
      stage_x(c3 + 1);
      VMC(0);                           // drains x + pre-staged next-round w
      __builtin_amdgcn_s_barrier();
    }
  }

  // ---- epilogue: bias + mask fused, fully-coalesced f32x2 stores ----
  const int cobase = cob * 64 + cos * 32;
  #pragma unroll
  for (int mi = 0; mi < 2; ++mi) {
    const f32x4 bv = *(const f32x4*)(bias + cobase + mi * 16 + kc * 4);
    #pragma unroll
    for (int ph = 0; ph < 2; ++ph) {
      const int oh = 2 * oy + ph;
      const unsigned char* mrow = many + ((size_t)b * OHH + oh) * OWW;
      #pragma unroll
      for (int ti = 0; ti < 4; ++ti) {
        const int ow0 = 2 * (ti * 16 + l15);
        const unsigned short m2 = *(const unsigned short*)(mrow + ow0);
        #pragma unroll
        for (int r = 0; r < 4; ++r) {
          const int co = cobase + mi * 16 + kc * 4 + r;
          f32x2 v;
          v.x = (m2 & 0x00FFu) ? acc[ph][0][mi][ti][r] + bv[r] : 0.f;
          v.y = (m2 & 0xFF00u) ? acc[ph][1][mi][ti][r] + bv[r] : 0.f;
          *(f32x2*)(out + (((size_t)(b * COUT + co)) * OHH + oh) * OWW + ow0) = v;
        }
      }
    }
  }
}

extern "C" void kernel_launch(void* const* d_in, const int* in_sizes, int n_in,
                              void* d_out, int out_size, void* d_ws, size_t ws_size,
                              hipStream_t stream) {
  const float* x    = (const float*)d_in[0];
  const int*   mask = (const int*)d_in[1];
  const float* w    = (const float*)d_in[2];
  const float* bias = (const float*)d_in[3];
  float* out = (float*)d_out;

  // ws: many 128KB | x4 14.6MB | w4 1.23MB  (~16MB)
  unsigned char*  many = (unsigned char*)d_ws;
  unsigned short* x4   = (unsigned short*)((char*)d_ws + 131072);
  unsigned short* w4   = (unsigned short*)((char*)d_ws + 131072 +
                                           (size_t)NB * 66 * X4_IYH_B);

  prep_k<<<752, 256, 0, stream>>>(x, mask, w, x4, w4, many);
  convt_mfma<<<512, 256, 0, stream>>>(x4, w4, bias, many, out);
}

// Round 17
// 54.119 us; speedup vs baseline: 1.1048x; 1.0185x over previous
//
#include <hip/hip_runtime.h>

// MyConvT: masked ConvTranspose2d, B=8, Cin=192, Cout=128, 64x64 -> 128x128,
// K=5, S=2, P=2, OP=1.  out = pooled_mask ? (convT(x,w) + bias) : 0
// Round 16 = r13 with the c3 round loop FULLY UNROLLED (was #pragma unroll 1).
// All GATE vmcnt selections and stage_u local-vs-next-round branches are on
// runtime c3 in r13; unrolling constant-folds every gate/tapid/slot to a
// literal and lets the scheduler smooth the round seams. No semantic change.
// Structure (unchanged): fused prep + convt at 2 blocks/CU, PAIR-PHASES
// (one vmcnt gate + one barrier per 2 taps), 5-slot w-ring staged 3 ahead
// with counted vmcnt(6) (tail 2/0), x 4-plane buffer restaged per ci64 round.
// Capacity audit: 6-slot ring needs 83KB > 80KB (2-block limit) — this
// family is LDS-capacity-optimal at 5 slots; (32co x 64ow) minimizes DS reads.

#define NB   8
#define CIN  192
#define COUT 128
#define HH   64
#define OHH  128
#define OWW  128
#define MH   132
#define MW   132

#define X4_IYH_B 27648               // bytes per (b,iyH): 3 c3 x 72 rows x 128B
#define PLANE_B  9216                // one c3 plane slice: 72 rows x 128B
#define XBUF_B   36864               // 4 planes
#define WOFF     36864
#define NSLOT    5
#define LDS_B    (XBUF_B + NSLOT * 8192)   // 77,824 <= 81,920 (2 blocks/CU)

typedef short bf16x8 __attribute__((ext_vector_type(8)));
typedef float f32x4  __attribute__((ext_vector_type(4)));
typedef float f32x2  __attribute__((ext_vector_type(2)));

static __device__ __forceinline__ unsigned short f2bf(float f) {
  union { float f; unsigned int u; } a; a.f = f;
  return (unsigned short)((a.u + 0x7fffu + ((a.u >> 16) & 1u)) >> 16);   // RNE
}

#define GLOAD_LDS16(gp, lp) __builtin_amdgcn_global_load_lds(                      \
    (const __attribute__((address_space(1))) void*)(gp),                           \
    (__attribute__((address_space(3))) void*)(lp), 16, 0, 0)

// ---------------- fused prep: xpose (528) | wpack (96) | pool (128) --------
__global__ __launch_bounds__(256) void prep_k(
    const float* __restrict__ x, const int* __restrict__ mask,
    const float* __restrict__ w, unsigned short* __restrict__ x4,
    unsigned short* __restrict__ w4, unsigned char* __restrict__ many) {
  const int bid = blockIdx.x, tid = threadIdx.x;

  if (bid < 528) {                                   // ---- xpose ----
    const int b = bid / 66, iyH = bid % 66;
    const int lane = tid & 63, wv = tid >> 6;
    unsigned short* pl = x4 + (size_t)(b * 66 + iyH) * (X4_IYH_B / 2);

    if (iyH == 0 || iyH == 65) {                     // zero halo plane
      for (int i = tid; i < X4_IYH_B / 16; i += 256)
        *(uint4*)(pl + i * 8) = make_uint4(0, 0, 0, 0);
      return;
    }
    const int iy = iyH - 1;
    if (tid < 48) {                                  // halo rows 0,65 per c3
      int c3 = tid >> 4, rr = (tid >> 3) & 1, ch = tid & 7;
      *(uint4*)(pl + (c3 * 72 + rr * 65) * 64 + ch * 8) = make_uint4(0, 0, 0, 0);
    }
    #pragma unroll
    for (int k = 0; k < 6; ++k) {
      int ci0 = wv * 48 + k * 8;
      int c3 = ci0 >> 6, cr = ci0 & 63;
      unsigned short p[8];
      #pragma unroll
      for (int e = 0; e < 8; ++e)
        p[e] = f2bf(x[(((size_t)b * CIN + ci0 + e) * HH + iy) * HH + lane]);
      uint4 v;
      v.x = (unsigned)p[0] | ((unsigned)p[1] << 16);
      v.y = (unsigned)p[2] | ((unsigned)p[3] << 16);
      v.z = (unsigned)p[4] | ((unsigned)p[5] << 16);
      v.w = (unsigned)p[6] | ((unsigned)p[7] << 16);
      *(uint4*)(pl + ((size_t)c3 * 72 + 1 + lane) * 64 + cr) = v;
    }
  } else if (bid < 624) {                            // ---- wpack ----
    int idx = (bid - 528) * 256 + tid;               // 0..24575
    int ci = idx % CIN, co = idx / CIN;
    int cob = co >> 6, c = co & 63, c3 = ci >> 6, cir = ci & 63;
    const float* src = w + (size_t)(ci * COUT + co) * 25;
    #pragma unroll
    for (int tap = 0; tap < 25; ++tap)
      w4[(size_t)((tap * 2 + cob) * 3 + c3) * 4096 + c * 64 + cir] = f2bf(src[tap]);
  } else {                                           // ---- pool (4 ow/thr) ----
    int g = (bid - 624) * 256 + tid;                 // 0..32767
    int owq = g & 31, oh = (g >> 5) & 127, b = g >> 12;
    const int* mp = mask + (b * MH + oh) * MW + owq * 4;
    int a0 = 0, a1 = 0, a2 = 0, a3 = 0;
    #pragma unroll
    for (int i = 0; i < 5; ++i) {
      int4 u = *(const int4*)(mp + i * MW);
      int4 v = *(const int4*)(mp + i * MW + 4);
      int c = u.z | u.w | v.x;                       // cols +2,+3,+4
      a0 |= u.x | u.y | c;
      a1 |= u.y | c | v.y;
      a2 |= c | v.y | v.z;
      a3 |= u.w | v.x | v.y | v.z | v.w;
    }
    *(uchar4*)(many + ((size_t)b * OHH + oh) * OWW + owq * 4) =
        make_uchar4(a0 ? 1 : 0, a1 ? 1 : 0, a2 ? 1 : 0, a3 ? 1 : 0);
  }
}

// ------------------------------ main kernel --------------------------------
// flat tap order (pairs aligned to group starts):
// t:      0  1  2  3  4  5  6  7  8  9 10 11 12 13 14 15 16 17 18 19 20 21 22 23 24
// (kh,kw) 00 01 10 11 02 03 12 13 04 14 20 21 30 31 22 23 32 33 24 34 40 41 42 43 44

#define VMC(N) asm volatile("s_waitcnt vmcnt(" #N ")" ::: "memory")

#define GATE(T)                                                                \
  { if ((T) == 24 && c3 == 2)      VMC(0);                                     \
    else if ((T) == 22 && c3 == 2) VMC(2);                                     \
    else                           VMC(6);                                     \
    __builtin_amdgcn_s_barrier(); }

#define BF_LOAD(KK, KJ)                                                        \
  { const int p_ = oyr + 2 - (KK);                                             \
    _Pragma("unroll") for (int k2 = 0; k2 < 2; ++k2)                           \
      _Pragma("unroll") for (int ti = 0; ti < 4; ++ti) {                       \
        const int row_ = ti * 16 + l15 + 2 - (KJ);                             \
        bfr[k2][ti] = *(const bf16x8*)(lds + p_ * PLANE_B + row_ * 128 +       \
                                       (((k2 * 4 + kc) ^ (row_ & 7)) << 4)); } }

#define AF_LOADJ(J, T)                                                         \
  { const char* ws_ = lds + WOFF + ((T) % 5) * 8192;                           \
    _Pragma("unroll") for (int k2 = 0; k2 < 2; ++k2)                           \
      _Pragma("unroll") for (int mi = 0; mi < 2; ++mi) {                       \
        const int row_ = cos * 32 + mi * 16 + l15;                             \
        afr[J][k2][mi] = *(const bf16x8*)(ws_ + row_ * 128 +                   \
                                          (((k2 * 4 + kc) ^ (l15 & 7)) << 4)); } }

#define MMJ(J, PH_, PW_)                                                       \
  { __builtin_amdgcn_s_setprio(1);                                             \
    _Pragma("unroll") for (int k2 = 0; k2 < 2; ++k2)                           \
      _Pragma("unroll") for (int mi = 0; mi < 2; ++mi)                         \
        _Pragma("unroll") for (int ti = 0; ti < 4; ++ti)                       \
          acc[PH_][PW_][mi][ti] = __builtin_amdgcn_mfma_f32_16x16x32_bf16(     \
              afr[J][k2][mi], bfr[k2][ti], acc[PH_][PW_][mi][ti], 0, 0, 0);    \
    __builtin_amdgcn_s_setprio(0); }

// pair-phase: stage taps T+3,T+4 | gate+barrier | (bf reload) | af x2 | MFMA x32
#define PAIRB(T, KK, KJ, PH0, PW0, PH1, PW1)                                   \
  { stage_u((T) + 3); stage_u((T) + 4); GATE(T)                                \
    BF_LOAD(KK, KJ) AF_LOADJ(0, T) AF_LOADJ(1, (T) + 1)                        \
    MMJ(0, PH0, PW0) MMJ(1, PH1, PW1) }
#define PAIRN(T, PH0, PW0, PH1, PW1)                                           \
  { stage_u((T) + 3); stage_u((T) + 4); GATE(T)                                \
    AF_LOADJ(0, T) AF_LOADJ(1, (T) + 1)                                        \
    MMJ(0, PH0, PW0) MMJ(1, PH1, PW1) }
// single-tap phase (t=24): stages only T+3 (keeps cross-round ledger uniform)
#define PH1B(T, KK, KJ, PH0, PW0)                                              \
  { stage_u((T) + 3); GATE(T)                                                  \
    BF_LOAD(KK, KJ) AF_LOADJ(0, T) MMJ(0, PH0, PW0) }

// grid 512: bid&7 = b (== XCD); qq = bid>>3: cob = qq&1, oyq = qq>>1 (0..31).
// 256 thr = 4 waves: cos = wv&1 (co 32-half), oyr = wv>>1 (oy row of pair).
__global__ __launch_bounds__(256, 2) void convt_mfma(
    const unsigned short* __restrict__ x4, const unsigned short* __restrict__ w4,
    const float* __restrict__ bias, const unsigned char* __restrict__ many,
    float* __restrict__ out) {
  __shared__ __align__(16) char lds[LDS_B];
  // tapid (kh*5+kw) by flat tap index
  constexpr int TID[25] = {0,1,5,6, 2,3,7,8, 4,9, 10,11,15,16, 12,13,17,18,
                           14,19, 20,21, 22,23, 24};

  const int tid = threadIdx.x, lane = tid & 63, wv = tid >> 6;
  const int l15 = lane & 15, kc = lane >> 4;
  const int cos = wv & 1, oyr = wv >> 1;
  const int b = blockIdx.x & 7, qq = blockIdx.x >> 3;
  const int cob = qq & 1, oyq = qq >> 1;
  const int oy0 = oyq * 2, oy = oy0 + oyr;
  // inverse-permuted source lane offset (matches read-side XOR swizzle)
  const int sswz = (lane >> 3) * 128 + (((lane & 7) ^ (lane >> 3)) << 4);

  const char* x4b = (const char*)x4 + (size_t)(b * 66 + oy0) * X4_IYH_B;
  const char* w4b = (const char*)w4 + cob * 24576;

  f32x4 acc[2][2][2][4];                 // [ph][pw][mi][ti]
  #pragma unroll
  for (int p = 0; p < 2; ++p)
    #pragma unroll
    for (int q2 = 0; q2 < 2; ++q2)
      #pragma unroll
      for (int i = 0; i < 2; ++i)
        #pragma unroll
        for (int j = 0; j < 4; ++j)
          acc[p][q2][i][j] = (f32x4){0.f, 0.f, 0.f, 0.f};

  auto stage_x = [&](int c3n) {
    #pragma unroll
    for (int j = 0; j < 9; ++j) {
      int qc = wv + 4 * j;                           // 36 chunks of 1KB
      int p = qc / 9, ch = qc % 9;
      GLOAD_LDS16(x4b + (size_t)p * X4_IYH_B + c3n * PLANE_B + ch * 1024 + sswz,
                  lds + p * PLANE_B + ch * 1024 + lane * 16);
    }
  };
  auto stage_w = [&](int tapid, int c3n, int slot) { // 2 x 1KB per wave
    const char* s = w4b + (size_t)tapid * 49152 + c3n * 8192 + wv * 2048 + sswz;
    char* d = lds + WOFF + slot * 8192 + wv * 2048 + lane * 16;
    GLOAD_LDS16(s, d);
    GLOAD_LDS16(s + 1024, d + 1024);
  };
  int c3 = 0;                                        // current ci64 round
  auto stage_u = [&](int u) {                        // stage local-or-next tap u
    if (u <= 24) stage_w(TID[u], c3, u % 5);
    else if (c3 < 2) stage_w(TID[u - 25], c3 + 1, (u - 25) % 5);
  };

  // ---- prologue: x round 0 + flat taps 0,1,2 (slots 0,1,2) ----
  stage_x(0);
  stage_w(TID[0], 0, 0);
  stage_w(TID[1], 0, 1);
  stage_w(TID[2], 0, 2);
  // no wait here: PAIRB(0)'s gate (vmcnt 6) admits taps 2..4 in flight.

  bf16x8 bfr[2][4], afr[2][2][2];
  #pragma unroll                                     // FULL unroll: c3 branches
  for (c3 = 0; c3 < 3; ++c3) {                       // fold to literals (r16)
    PAIRB(0,  0, 0,  0, 0,  0, 1)       // t0 (0,0), t1 (0,1) | bf g(kk0,kj0)
    PAIRN(2,         1, 0,  1, 1)       // t2 (1,0), t3 (1,1)
    PAIRB(4,  0, 1,  0, 0,  0, 1)       // t4 (0,2), t5 (0,3) | bf g(kk0,kj1)
    PAIRN(6,         1, 0,  1, 1)       // t6 (1,2), t7 (1,3)
    PAIRB(8,  0, 2,  0, 0,  1, 0)       // t8 (0,4), t9 (1,4) | bf g(kk0,kj2)
    PAIRB(10, 1, 0,  0, 0,  0, 1)       // t10 (2,0), t11 (2,1) | bf g(kk1,kj0)
    PAIRN(12,        1, 0,  1, 1)       // t12 (3,0), t13 (3,1)
    PAIRB(14, 1, 1,  0, 0,  0, 1)       // t14 (2,2), t15 (2,3) | bf g(kk1,kj1)
    PAIRN(16,        1, 0,  1, 1)       // t16 (3,2), t17 (3,3)
    PAIRB(18, 1, 2,  0, 0,  1, 0)       // t18 (2,4), t19 (3,4) | bf g(kk1,kj2)
    PAIRB(20, 2, 0,  0, 0,  0, 1)       // t20 (4,0), t21 (4,1) | bf g(kk2,kj0)
    PAIRB(22, 2, 1,  0, 0,  0, 1)       // t22 (4,2), t23 (4,3) | bf g(kk2,kj1)
    PH1B (24, 2, 2,  0, 0)              // t24 (4,4)           | bf g(kk2,kj2)
    if (c3 < 2) {                       // round boundary: restage x planes
      __builtin_amdgcn_s_barrier();     // all waves done reading xbuf
      stage_x(c3 + 1);
      VMC(0);                           // drains x + pre-staged next-round w
      __builtin_amdgcn_s_barrier();
    }
  }

  // ---- epilogue: bias + mask fused, fully-coalesced f32x2 stores ----
  const int cobase = cob * 64 + cos * 32;
  #pragma unroll
  for (int mi = 0; mi < 2; ++mi) {
    const f32x4 bv = *(const f32x4*)(bias + cobase + mi * 16 + kc * 4);
    #pragma unroll
    for (int ph = 0; ph < 2; ++ph) {
      const int oh = 2 * oy + ph;
      const unsigned char* mrow = many + ((size_t)b * OHH + oh) * OWW;
      #pragma unroll
      for (int ti = 0; ti < 4; ++ti) {
        const int ow0 = 2 * (ti * 16 + l15);
        const unsigned short m2 = *(const unsigned short*)(mrow + ow0);
        #pragma unroll
        for (int r = 0; r < 4; ++r) {
          const int co = cobase + mi * 16 + kc * 4 + r;
          f32x2 v;
          v.x = (m2 & 0x00FFu) ? acc[ph][0][mi][ti][r] + bv[r] : 0.f;
          v.y = (m2 & 0xFF00u) ? acc[ph][1][mi][ti][r] + bv[r] : 0.f;
          *(f32x2*)(out + (((size_t)(b * COUT + co)) * OHH + oh) * OWW + ow0) = v;
        }
      }
    }
  }
}

extern "C" void kernel_launch(void* const* d_in, const int* in_sizes, int n_in,
                              void* d_out, int out_size, void* d_ws, size_t ws_size,
                              hipStream_t stream) {
  const float* x    = (const float*)d_in[0];
  const int*   mask = (const int*)d_in[1];
  const float* w    = (const float*)d_in[2];
  const float* bias = (const float*)d_in[3];
  float* out = (float*)d_out;

  // ws: many 128KB | x4 14.6MB | w4 1.23MB  (~16MB)
  unsigned char*  many = (unsigned char*)d_ws;
  unsigned short* x4   = (unsigned short*)((char*)d_ws + 131072);
  unsigned short* w4   = (unsigned short*)((char*)d_ws + 131072 +
                                           (size_t)NB * 66 * X4_IYH_B);

  prep_k<<<752, 256, 0, stream>>>(x, mask, w, x4, w4, many);
  convt_mfma<<<512, 256, 0, stream>>>(x4, w4, bias, many, out);
}